// Round 11
// baseline (291.113 us; speedup 1.0000x reference)
//
#include <hip/hip_runtime.h>
#include <stdint.h>

#define DIM 512
#define ROWS_PER_BLOCK 64                // 4 waves x 16 rows (phase B)
#define N_CHUNKS 32                      // 32 chunks of 16 e-columns
#define CHUNK_BYTES 8192                 // 16 rows x 512 fp8 (atom-rotated, no pad)
#define WS_BYTES (N_CHUNKS * CHUNK_BYTES)   // 262144 (R image)
#define N_BUF 4                          // LDS ring buffers (32 KB total)
#define PREFETCH 3                       // stage depth: chunk EB+3 in flight

typedef __attribute__((ext_vector_type(4))) float f32x4;
typedef __attribute__((ext_vector_type(2))) float f32x2;
typedef __attribute__((ext_vector_type(4))) int   i32x4;

// k-permutation (validated): position q = g*8+j within 32-k block kk holds
// k = 32*kk + (j<4 ? 4g+j : 16+4g+(j-4)). Puts epilogue value delta[r][e]
// in-lane: e = 16*eb + 4g + i  <->  frag[eb>>1], byte (eb&1)*4 + i.
static __device__ __forceinline__ int kperm(int kk, int q) {
  int g = q >> 3, j = q & 7;
  int r = (j < 4) ? (g * 4 + j) : (16 + g * 4 + (j - 4));
  return kk * 32 + r;
}

// Build fp8 image of 64*(S - I), pre-swizzled: chunk -> 16 rows (e_l) x 512 B.
// Atom (P,g) of row e_l stored at physical slot ((4P+g)+e_l)&31 (bank spread).
__global__ void prep_R(const float* __restrict__ S, uint32_t* __restrict__ ws) {
  int idx = blockIdx.x * blockDim.x + threadIdx.x;   // word index
  if (idx >= WS_BYTES / 4) return;
  int b     = idx * 4;
  int chunk = b >> 13;
  int e_l   = (b >> 9) & 15;
  int inrow = b & 511;
  int slot  = inrow >> 4;
  int bia   = inrow & 15;                // byte-in-atom base (0,4,8,12)
  int la    = (slot - e_l) & 31;         // logical atom = 4P+g
  int P = la >> 2, g = la & 3;
  int e = chunk * 16 + e_l;
  float v[4];
#pragma unroll
  for (int t = 0; t < 4; ++t) {
    int bb = bia + t;                    // byte in atom 0..15
    int j  = bb & 7;
    int kk = 2 * P + (bb >> 3);
    int k  = kperm(kk, g * 8 + j);
    v[t] = 64.0f * (S[k * DIM + e] - (k == e ? 1.0f : 0.0f));   // x64: e4m3 range
  }
  int w = __builtin_amdgcn_cvt_pk_fp8_f32(v[0], v[1], 0, false);
  w     = __builtin_amdgcn_cvt_pk_fp8_f32(v[2], v[3], w, true);
  ws[idx] = (uint32_t)w;
}

// Nontemporal load (no-allocate / evict-first). Round-10 lesson: nt does NOT
// bypass L3 lookups — resident lines still hit (FETCH stayed at 132 MB = half
// the input). It does prevent further pollution and measurably speeds the
// stream (round-5 dp: 102 -> <78 us). ext_vector f32x4 required (round-7).
static __device__ __forceinline__ f32x4 ntload4(const float* p) {
  return __builtin_nontemporal_load((const f32x4*)p);
}

// ---- Phase A: pure-streaming delta+pack, 4 ROWS PER ITERATION.
// Round-10 evidence: streaming rate tracks streaming-wave count and in-flight
// depth (fused 8 waves/CU @ 4-8 loads: 2.87 TB/s; dp 20+ waves/CU @ 8 loads:
// ~3.5-3.8). This version: 16 nt loads in flight per wave (64 VGPR payload,
// ~90 total), grid 4096 -> one 4-row batch per wave, max concurrent streamers.
// Per-row byte layout & reduce order IDENTICAL to validated round-4/5 dp.
__global__ __launch_bounds__(256)
void delta_pack(const float* __restrict__ X, const float* __restrict__ XF,
                unsigned long long* __restrict__ img, float* __restrict__ sums,
                int nrows) {
  const int lane = threadIdx.x & 63;
  const int wid  = blockIdx.x * (blockDim.x >> 6) + (threadIdx.x >> 6);
  const int nw   = gridDim.x * (blockDim.x >> 6);
  const int g    = lane & 3;
  const int h    = (lane >> 2) & 1;      // half: 0 -> d0..d3, 1 -> d4..d7
  const int kA   = lane >> 3;            // kk of quad 'lane'; quad lane+64 -> kk=8+kA

  for (int row = wid; row < nrows; row += 4 * nw) {
    int r[4];
    f32x4 xa[4], fa[4], xb[4], fb[4];
#pragma unroll
    for (int k = 0; k < 4; ++k) {
      r[k] = row + k * nw;
      int rc = (r[k] < nrows) ? r[k] : (nrows - 1);   // clamp addr; store guarded
      const f32x4* xq = (const f32x4*)(X  + (size_t)rc * DIM);
      const f32x4* fq = (const f32x4*)(XF + (size_t)rc * DIM);
      xa[k] = ntload4((const float*)(xq + lane));
      fa[k] = ntload4((const float*)(fq + lane));
      xb[k] = ntload4((const float*)(xq + lane + 64));
      fb[k] = ntload4((const float*)(fq + lane + 64));
    }

#pragma unroll
    for (int k = 0; k < 4; ++k) {
      if (r[k] >= nrows) break;
      f32x4 dA = xa[k] - fa[k];
      f32x4 dB = xb[k] - fb[k];
      float ps = dA[0]*dA[0] + dA[1]*dA[1] + dA[2]*dA[2] + dA[3]*dA[3]
               + dB[0]*dB[0] + dB[1]*dB[1] + dB[2]*dB[2] + dB[3]*dB[3];
      int wA = __builtin_amdgcn_cvt_pk_fp8_f32(dA[0], dA[1], 0, false);
      wA     = __builtin_amdgcn_cvt_pk_fp8_f32(dA[2], dA[3], wA, true);
      int wB = __builtin_amdgcn_cvt_pk_fp8_f32(dB[0], dB[1], 0, false);
      wB     = __builtin_amdgcn_cvt_pk_fp8_f32(dB[2], dB[3], wB, true);
      int pA = __shfl_xor(wA, 4);        // partner lane l^4 = other half, same (g,kk)
      int pB = __shfl_xor(wB, 4);
      unsigned long long L;
      int kk;
      if (h == 0) { L = ((unsigned long long)(unsigned)pA << 32) | (unsigned)wA; kk = kA; }
      else        { L = ((unsigned long long)(unsigned)wB << 32) | (unsigned)pB; kk = 8 + kA; }
      img[(size_t)r[k] * 64 + g * 16 + kk] = L;
      ps += __shfl_xor(ps, 1);  ps += __shfl_xor(ps, 2);  ps += __shfl_xor(ps, 4);
      ps += __shfl_xor(ps, 8);  ps += __shfl_xor(ps, 16); ps += __shfl_xor(ps, 32);
      if (lane == 0) sums[r[k]] = ps;
    }
  }
}

// Stage one 8 KB R-chunk into LDS (async direct-to-LDS, width 16, linear).
static __device__ __forceinline__ void stage_chunk(const uint32_t* __restrict__ ws,
                                                   int eb, char* dst, int tid) {
  const uint32_t* src = ws + (size_t)eb * (CHUNK_BYTES / 4);
#pragma unroll
  for (int r = 0; r < 2; ++r) {                      // 512 x 16B slots
    int idx = r * 256 + tid;
    __builtin_amdgcn_global_load_lds(
        (const __attribute__((address_space(1))) void*)(src + idx * 4),
        (__attribute__((address_space(3))) void*)(dst + idx * 16),
        16, 0, 0);
  }
}

// ---- Phase 0 (legacy fused path only; template-unrolled, cached loads) ----
template <int KK>
struct P0 {
  static __device__ __forceinline__ void run(const float* __restrict__ xr,
                                             const float* __restrict__ fr,
                                             int g, long long (&fragL)[16], float& sumsq) {
    const float4 a0 = *(const float4*)(xr + KK * 32 + 4 * g);
    const float4 b0 = *(const float4*)(fr + KK * 32 + 4 * g);
    const float4 a1 = *(const float4*)(xr + KK * 32 + 16 + 4 * g);
    const float4 b1 = *(const float4*)(fr + KK * 32 + 16 + 4 * g);
    float d0 = a0.x - b0.x, d1 = a0.y - b0.y, d2 = a0.z - b0.z, d3 = a0.w - b0.w;
    float d4 = a1.x - b1.x, d5 = a1.y - b1.y, d6 = a1.z - b1.z, d7 = a1.w - b1.w;
    sumsq += d0*d0 + d1*d1 + d2*d2 + d3*d3 + d4*d4 + d5*d5 + d6*d6 + d7*d7;
    int lo = __builtin_amdgcn_cvt_pk_fp8_f32(d0, d1, 0, false);
    lo     = __builtin_amdgcn_cvt_pk_fp8_f32(d2, d3, lo, true);
    int hi = __builtin_amdgcn_cvt_pk_fp8_f32(d4, d5, 0, false);
    hi     = __builtin_amdgcn_cvt_pk_fp8_f32(d6, d7, hi, true);
    fragL[KK] = (long long)(((unsigned long long)(unsigned)hi << 32) | (unsigned)lo);
    P0<KK + 1>::run(xr, fr, g, fragL, sumsq);
  }
};
template <>
struct P0<16> {
  static __device__ __forceinline__ void run(const float*, const float*, int,
                                             long long (&)[16], float&) {}
};

// ---- K-loop over 8 atom-steps; each b128 feeds two fp8 MFMAs ----
template <int P>
struct KLoop {
  static __device__ __forceinline__ void run(const char* __restrict__ rowbase,
                                             int g, int m,
                                             const long long (&fragL)[16],
                                             f32x4& c0, f32x4& c1) {
    int off = ((4 * P + g + m) & 31) * 16;           // rotated atom slot
    i32x4 a = *(const i32x4*)(rowbase + off);
    long long A0 = (long long)(((unsigned long long)(unsigned)a[1] << 32) | (unsigned)a[0]);
    long long A1 = (long long)(((unsigned long long)(unsigned)a[3] << 32) | (unsigned)a[2]);
    c0 = __builtin_amdgcn_mfma_f32_16x16x32_fp8_fp8(A0, fragL[2 * P],     c0, 0, 0, 0);
    c1 = __builtin_amdgcn_mfma_f32_16x16x32_fp8_fp8(A1, fragL[2 * P + 1], c1, 0, 0, 0);
    KLoop<P + 1>::run(rowbase, g, m, fragL, c0, c1);
  }
};
template <>
struct KLoop<8> {
  static __device__ __forceinline__ void run(const char*, int, int,
                                             const long long (&)[16], f32x4&, f32x4&) {}
};

// ---- Chunk loop: 4-buffer LDS ring, depth-3 prefetch, ONE raw s_barrier per
// chunk with counted vmcnt (round-3 validated). ----
template <int EB>
struct ChunkLoop {
  static __device__ __forceinline__ void run(const uint32_t* __restrict__ ws,
                                             char* __restrict__ sbase,
                                             int tid, int m, int g,
                                             const long long (&fragL)[16], float& part) {
    if constexpr (EB <= N_CHUNKS - 3)
      asm volatile("s_waitcnt vmcnt(4) lgkmcnt(0)" ::: "memory");
    else if constexpr (EB == N_CHUNKS - 2)
      asm volatile("s_waitcnt vmcnt(2) lgkmcnt(0)" ::: "memory");
    else
      asm volatile("s_waitcnt vmcnt(0) lgkmcnt(0)" ::: "memory");
    __builtin_amdgcn_s_barrier();

    if constexpr (EB + PREFETCH < N_CHUNKS)
      stage_chunk(ws, EB + PREFETCH,
                  sbase + ((EB + PREFETCH) & (N_BUF - 1)) * CHUNK_BYTES, tid);

    const char* rowbase = sbase + (EB & (N_BUF - 1)) * CHUNK_BYTES + m * 512;
    f32x4 c0 = {0.f, 0.f, 0.f, 0.f}, c1 = {0.f, 0.f, 0.f, 0.f};
    KLoop<0>::run(rowbase, g, m, fragL, c0, c1);

    // Epilogue: C row (g*4+i)=e_local; delta[r][e] is byte (EB&1)*4+i of fragL[EB>>1].
    constexpr int kk = EB >> 1;
    int src = (int)(fragL[kk] >> ((EB & 1) * 32));
    f32x2 f01 = __builtin_amdgcn_cvt_pk_f32_fp8(src, false);
    f32x2 f23 = __builtin_amdgcn_cvt_pk_f32_fp8(src, true);
    part += (c0[0] + c1[0]) * f01[0] + (c0[1] + c1[1]) * f01[1]
          + (c0[2] + c1[2]) * f23[0] + (c0[3] + c1[3]) * f23[1];

    ChunkLoop<EB + 1>::run(ws, sbase, tid, m, g, fragL, part);
  }
};
template <>
struct ChunkLoop<N_CHUNKS> {
  static __device__ __forceinline__ void run(const uint32_t*, char*, int, int, int,
                                             const long long (&)[16], float&) {}
};

// out[row] = fp32 sumsq(delta) + (1/64) * delta^T (64R) delta  via fp8 MFMA.
// FROM_IMG=true (split path): fragL loaded from phase-A image (128 B/lane,
// L2/L3-resident) — no X/XF streaming here. FROM_IMG=false: legacy fused path.
template <bool FROM_IMG>
__global__ __launch_bounds__(256, 2)
void mahal_main(const float* __restrict__ X, const float* __restrict__ XF,
                const uint32_t* __restrict__ ws,
                const unsigned long long* __restrict__ img,
                const float* __restrict__ sums, float* __restrict__ out) {
  __shared__ __align__(16) char sA[N_BUF][CHUNK_BYTES];   // 32 KB

  const int tid  = threadIdx.x;
  const int lane = tid & 63;
  const int wv   = tid >> 6;
  const int m    = lane & 15;          // delta row within wave
  const int g    = lane >> 4;          // lane group
  const int row  = blockIdx.x * ROWS_PER_BLOCK + wv * 16 + m;

  // Prologue: 3 chunks in flight before any compute.
  stage_chunk(ws, 0, sA[0], tid);
  stage_chunk(ws, 1, sA[1], tid);
  stage_chunk(ws, 2, sA[2], tid);

  long long fragL[16];
  float sumsq = 0.f;
  if constexpr (FROM_IMG) {
    const i32x4* ib = (const i32x4*)(img + (size_t)row * 64 + (size_t)g * 16);
    i32x4 t[8];
#pragma unroll
    for (int j = 0; j < 8; ++j) t[j] = ib[j];
#pragma unroll
    for (int j = 0; j < 8; ++j) {
      fragL[2 * j]     = (long long)(((unsigned long long)(unsigned)t[j][1] << 32) | (unsigned)t[j][0]);
      fragL[2 * j + 1] = (long long)(((unsigned long long)(unsigned)t[j][3] << 32) | (unsigned)t[j][2]);
    }
  } else {
    const float* xr = X  + (size_t)row * DIM;
    const float* fr = XF + (size_t)row * DIM;
    P0<0>::run(xr, fr, g, fragL, sumsq);
    sumsq += __shfl_xor(sumsq, 16);
    sumsq += __shfl_xor(sumsq, 32);
  }

  float part = 0.f;
  ChunkLoop<0>::run(ws, &sA[0][0], tid, m, g, fragL, part);

  part += __shfl_xor(part, 16);
  part += __shfl_xor(part, 32);
  if (g == 0) {
    float base = FROM_IMG ? sums[row] : sumsq;
    out[row] = base + part * 0.015625f;   // 1/64 undoes R scaling
  }
}

// Safety-net (only if ws_size is unexpectedly small): naive fp32, correct.
__global__ void mahal_naive(const float* __restrict__ X, const float* __restrict__ XF,
                            const float* __restrict__ S, float* __restrict__ out, int n) {
  int row = blockIdx.x * blockDim.x + threadIdx.x;
  if (row >= n) return;
  const float* xr = X + (size_t)row * DIM;
  const float* fr = XF + (size_t)row * DIM;
  float acc = 0.f;
  for (int d = 0; d < DIM; ++d) {
    float dd = xr[d] - fr[d];
    float inner = 0.f;
    for (int e = 0; e < DIM; ++e) inner += S[d * DIM + e] * (xr[e] - fr[e]);
    acc += dd * inner;
  }
  out[row] = acc;
}

extern "C" void kernel_launch(void* const* d_in, const int* in_sizes, int n_in,
                              void* d_out, int out_size, void* d_ws, size_t ws_size,
                              hipStream_t stream) {
  const float* X  = (const float*)d_in[0];
  const float* XF = (const float*)d_in[1];
  const float* S  = (const float*)d_in[2];
  float* out = (float*)d_out;
  const int N = in_sizes[0] / DIM;

  const size_t img_bytes  = (size_t)N * 512;        // fp8 delta image
  const size_t split_need = (size_t)WS_BYTES + img_bytes + (size_t)N * 4;

  if ((N % ROWS_PER_BLOCK) != 0 || ws_size < (size_t)WS_BYTES) {
    mahal_naive<<<(N + 63) / 64, 64, 0, stream>>>(X, XF, S, out, N);
    return;
  }

  uint32_t* ws = (uint32_t*)d_ws;
  prep_R<<<(WS_BYTES / 4 + 255) / 256, 256, 0, stream>>>(S, ws);

  if (ws_size >= split_need) {
    unsigned long long* img = (unsigned long long*)((char*)d_ws + WS_BYTES);
    float* sums = (float*)((char*)d_ws + WS_BYTES + img_bytes);
    delta_pack<<<4096, 256, 0, stream>>>(X, XF, img, sums, N);
    mahal_main<true><<<N / ROWS_PER_BLOCK, 256, 0, stream>>>(X, XF, ws, img, sums, out);
  } else {
    mahal_main<false><<<N / ROWS_PER_BLOCK, 256, 0, stream>>>(X, XF, ws, nullptr, nullptr, out);
  }
}